// Round 15
// baseline (227.514 us; speedup 1.0000x reference)
//
#include <hip/hip_runtime.h>

// B=2, L=2048, D=1024, H=16, DK=DV=64, M=4096.
// R19: fuse LayerNorm into k_gemm_op via per-row-group tile counter (safe,
//      no spin): each of the 8 blocks per 64-row group does release-fence +
//      agent-scope atomicAdd after writing its Y slice; the LAST arriver
//      acquires and LayerNorms the group's 64 rows (1 wave / 16 rows,
//      lane-local partials + 6-step shfl_xor — numerically identical to the
//      old k_ln). Counter zeroed by k_prep (stream-ordered). k_ln deleted.
//      Everything else frozen at R18 (best 186.2us; R18 reproduced 187.3).

typedef __bf16 bf16;
typedef __bf16 bf16x2 __attribute__((ext_vector_type(2)));
typedef __bf16 bf16x4 __attribute__((ext_vector_type(4)));
typedef __bf16 bf16x8 __attribute__((ext_vector_type(8)));
typedef float floatx4 __attribute__((ext_vector_type(4)));
typedef int intx4 __attribute__((ext_vector_type(4)));

#define MFMA16(a, b, c) __builtin_amdgcn_mfma_f32_16x16x32_bf16((a), (b), (c), 0, 0, 0)

__device__ __forceinline__ void gll16(const bf16* g, bf16* l) {
  __builtin_amdgcn_global_load_lds((const __attribute__((address_space(1))) void*)g,
                                   (__attribute__((address_space(3))) void*)l, 16, 0, 0);
}

// ---------------- merged prep: z<4 -> transpose W[z] to WT bf16; z>=4 -> x fp32->bf16 ----------------
// z==0 (Wq) rows are pre-scaled by 0.125*log2(e). z==7/block(0,0) zeroes the LN tile counter.
__global__ __launch_bounds__(256) void k_prep(const float* __restrict__ x,
                                              const float* __restrict__ Wq, const float* __restrict__ Wk,
                                              const float* __restrict__ Wv, const float* __restrict__ Wo,
                                              bf16* __restrict__ xb, bf16* __restrict__ WT,
                                              int* __restrict__ cnt) {
  __shared__ float tile[32][33];
  const int z = blockIdx.z;
  const int tx = threadIdx.x, ty = threadIdx.y;
  if (z < 4) {
    const float* W = (z == 0) ? Wq : (z == 1) ? Wk : (z == 2) ? Wv : Wo;
    const float sc = (z == 0) ? 0.18033688f : 1.0f;  // 1/8 * log2(e) folded into Wq
    const int n0 = blockIdx.x * 32, k0 = blockIdx.y * 32;
#pragma unroll
    for (int j = 0; j < 32; j += 8)
      tile[ty + j][tx] = W[(size_t)(k0 + ty + j) * 1024 + n0 + tx] * sc;
    __syncthreads();
#pragma unroll
    for (int j = 0; j < 32; j += 8)
      WT[(size_t)(z * 1024 + n0 + ty + j) * 1024 + k0 + tx] = (bf16)tile[tx][ty + j];
  } else {
    // quarter (z-4) of x: 1024 blocks x 256 threads x 4 floats
    const int blin = blockIdx.y * 32 + blockIdx.x;
    const int tid = ty * 32 + tx;
    if (z == 7 && blin == 0 && tid < 64) cnt[tid] = 0;  // zero LN group counters
    const size_t i = (((size_t)(z - 4) * 1024 + blin) * 256 + tid) * 4;
    const float4 v = *reinterpret_cast<const float4*>(x + i);
    bf16x4 o = {(bf16)v.x, (bf16)v.y, (bf16)v.z, (bf16)v.w};
    *reinterpret_cast<bf16x4*>(xb + i) = o;
  }
}

// ---------------- QKV GEMM: 128x128, dbuf ring-2 counted vmcnt ----------------
template <int MODE>
__global__ __launch_bounds__(256) void k_gemm(const bf16* __restrict__ A, const bf16* __restrict__ Bt,
                                              const float* __restrict__ X, float* __restrict__ Y,
                                              bf16* __restrict__ QB, bf16* __restrict__ KB,
                                              bf16* __restrict__ VTB) {
  __shared__ __align__(16) bf16 As[2 * 128 * 64];  // slot c^(r&7) holds chunk c of row r
  __shared__ __align__(16) bf16 Bs[2 * 128 * 64];
  const int t = threadIdx.x;
  const int lane = t & 63, wv = t >> 6;
  const int qd = lane >> 4, col = lane & 15;
  const int c7 = col & 7;
  const int wm = wv >> 1, wn = wv & 1;
  const int m0 = blockIdx.x * 128, n0 = blockIdx.y * 128;
  const int srow = wv * 8 + (lane >> 3);
  const int scol = ((lane & 7) ^ (lane >> 3)) * 8;
  const bf16* Ag = A + (size_t)(m0 + srow) * 1024 + scol;
  const bf16* Bg = Bt + (size_t)(n0 + srow) * 1024 + scol;

  floatx4 acc[4][4] = {};

#define GSTAGE(bu, ti)                                                                              \
  do {                                                                                              \
    _Pragma("unroll") for (int rd = 0; rd < 4; rd++) {                                              \
      gll16(Ag + (size_t)rd * 32 * 1024 + (ti) * 64, As + (bu) * 8192 + (rd * 32 + wv * 8) * 64);   \
      gll16(Bg + (size_t)rd * 32 * 1024 + (ti) * 64, Bs + (bu) * 8192 + (rd * 32 + wv * 8) * 64);   \
    }                                                                                               \
  } while (0)

#define GCOMP(bu)                                                                                   \
  do {                                                                                              \
    const bf16* as_ = As + (bu) * 8192;                                                             \
    const bf16* bs_ = Bs + (bu) * 8192;                                                             \
    _Pragma("unroll") for (int ks = 0; ks < 2; ks++) {                                              \
      bf16x8 af[4], bfr[4];                                                                         \
      _Pragma("unroll") for (int i = 0; i < 4; i++)                                                 \
        af[i] = *reinterpret_cast<const bf16x8*>(as_ + (wm * 64 + i * 16 + col) * 64 +              \
                                                 ((ks * 4 + qd) ^ c7) * 8);                         \
      _Pragma("unroll") for (int i = 0; i < 4; i++)                                                 \
        bfr[i] = *reinterpret_cast<const bf16x8*>(bs_ + (wn * 64 + i * 16 + col) * 64 +             \
                                                  ((ks * 4 + qd) ^ c7) * 8);                        \
      _Pragma("unroll") for (int i = 0; i < 4; i++)                                                 \
        _Pragma("unroll") for (int j = 0; j < 4; j++)                                               \
          acc[i][j] = MFMA16(af[i], bfr[j], acc[i][j]);                                             \
    }                                                                                               \
  } while (0)

  // prologue: tiles 0,1 -> bufs 0,1 (16 loads in flight)
  GSTAGE(0, 0);
  GSTAGE(1, 1);
  // steady state, distance-2: vmcnt(8) -> tile t landed (t+1's 8 loads remain
  // in flight); after compute+barrier, refill this buffer with tile t+2.
  for (int ti = 0; ti < 14; ti += 2) {
    asm volatile("s_waitcnt vmcnt(8)" ::: "memory");
    __builtin_amdgcn_s_barrier();
    GCOMP(0);
    __builtin_amdgcn_s_barrier();
    if (ti + 2 < 16) GSTAGE(0, ti + 2);
    asm volatile("s_waitcnt vmcnt(8)" ::: "memory");
    __builtin_amdgcn_s_barrier();
    GCOMP(1);
    __builtin_amdgcn_s_barrier();
    if (ti + 3 < 16) GSTAGE(1, ti + 3);
  }
  // tail: tiles 14 (buf0), 15 (buf1)
  asm volatile("s_waitcnt vmcnt(8)" ::: "memory");
  __builtin_amdgcn_s_barrier();
  GCOMP(0);
  asm volatile("s_waitcnt vmcnt(0)" ::: "memory");
  __builtin_amdgcn_s_barrier();
  GCOMP(1);
#undef GSTAGE
#undef GCOMP

#pragma unroll
  for (int i = 0; i < 4; i++) {
#pragma unroll
    for (int j = 0; j < 4; j++) {
      const int mb = m0 + wm * 64 + i * 16 + qd * 4;
      const int n = n0 + wn * 64 + j * 16 + col;
      if (MODE == 0) {
        const int seg = n >> 10;
        const int h = (n & 1023) >> 6, dd = n & 63;
#pragma unroll
        for (int r = 0; r < 4; r++) {
          const int m = mb + r;
          const int bb = m >> 11, l = m & 2047;
          const float v = acc[i][j][r];
          if (seg == 0)
            QB[((size_t)(bb * 16 + h) * 2048 + l) * 64 + dd] = (bf16)v;  // scale folded into Wq
          else if (seg == 1)
            KB[((size_t)(bb * 16 + h) * 2048 + l) * 64 + dd] = (bf16)v;
          else
            VTB[((size_t)(bb * 16 + h) * 64 + dd) * 2048 + l] = (bf16)v;
        }
      } else {
#pragma unroll
        for (int r = 0; r < 4; r++) {
          const int m = mb + r;
          Y[(size_t)m * 1024 + n] = acc[i][j][r] + X[(size_t)m * 1024 + n];
        }
      }
    }
  }
}

// ---------------- output projection + fused LayerNorm ----------------
// Y = OB * Wo^T + x; last block per 64-row group LayerNorms the group.
// 64x128 tile, grid (64,8); 4 waves as 2m x 2n; wave tile 32x64 (acc[2][4]).
__global__ __launch_bounds__(256) void k_gemm_op(const bf16* __restrict__ A, const bf16* __restrict__ Bt,
                                                 const float* __restrict__ X, float* __restrict__ Y,
                                                 const float* __restrict__ gamma, const float* __restrict__ beta,
                                                 float* __restrict__ out, int* __restrict__ cnt) {
  __shared__ __align__(16) bf16 As[2 * 64 * 64];   // slot c^(r&7) holds chunk c of row r
  __shared__ __align__(16) bf16 Bs[2 * 128 * 64];
  const int t = threadIdx.x;
  const int lane = t & 63, wv = t >> 6;
  const int qd = lane >> 4, col = lane & 15;
  const int c7 = col & 7;
  const int wm = wv >> 1, wn = wv & 1;
  const int m0 = blockIdx.x * 64, n0 = blockIdx.y * 128;
  const int srow = wv * 8 + (lane >> 3);           // 0..31
  const int scol = ((lane & 7) ^ (lane >> 3)) * 8;
  const bf16* Ag = A + (size_t)(m0 + srow) * 1024 + scol;
  const bf16* Bg = Bt + (size_t)(n0 + srow) * 1024 + scol;

  floatx4 acc[2][4] = {};

#define GSTAGE(bu, ti)                                                                              \
  do {                                                                                              \
    _Pragma("unroll") for (int rd = 0; rd < 2; rd++)                                                \
      gll16(Ag + (size_t)rd * 32 * 1024 + (ti) * 64, As + (bu) * 4096 + (rd * 32 + wv * 8) * 64);   \
    _Pragma("unroll") for (int rd = 0; rd < 4; rd++)                                                \
      gll16(Bg + (size_t)rd * 32 * 1024 + (ti) * 64, Bs + (bu) * 8192 + (rd * 32 + wv * 8) * 64);   \
  } while (0)

#define GCOMP(bu)                                                                                   \
  do {                                                                                              \
    const bf16* as_ = As + (bu) * 4096;                                                             \
    const bf16* bs_ = Bs + (bu) * 8192;                                                             \
    _Pragma("unroll") for (int ks = 0; ks < 2; ks++) {                                              \
      bf16x8 af[2], bfr[4];                                                                         \
      _Pragma("unroll") for (int i = 0; i < 2; i++)                                                 \
        af[i] = *reinterpret_cast<const bf16x8*>(as_ + (wm * 32 + i * 16 + col) * 64 +              \
                                                 ((ks * 4 + qd) ^ c7) * 8);                         \
      _Pragma("unroll") for (int j = 0; j < 4; j++)                                                 \
        bfr[j] = *reinterpret_cast<const bf16x8*>(bs_ + (wn * 64 + j * 16 + col) * 64 +             \
                                                  ((ks * 4 + qd) ^ c7) * 8);                        \
      _Pragma("unroll") for (int i = 0; i < 2; i++)                                                 \
        _Pragma("unroll") for (int j = 0; j < 4; j++)                                               \
          acc[i][j] = MFMA16(af[i], bfr[j], acc[i][j]);                                             \
    }                                                                                               \
  } while (0)

  // prologue: tiles 0,1 (6 loads each; 12 in flight)
  GSTAGE(0, 0);
  GSTAGE(1, 1);
  for (int ti = 0; ti < 14; ti += 2) {
    asm volatile("s_waitcnt vmcnt(6)" ::: "memory");
    __builtin_amdgcn_s_barrier();
    GCOMP(0);
    __builtin_amdgcn_s_barrier();
    if (ti + 2 < 16) GSTAGE(0, ti + 2);
    asm volatile("s_waitcnt vmcnt(6)" ::: "memory");
    __builtin_amdgcn_s_barrier();
    GCOMP(1);
    __builtin_amdgcn_s_barrier();
    if (ti + 3 < 16) GSTAGE(1, ti + 3);
  }
  asm volatile("s_waitcnt vmcnt(6)" ::: "memory");
  __builtin_amdgcn_s_barrier();
  GCOMP(0);
  asm volatile("s_waitcnt vmcnt(0)" ::: "memory");
  __builtin_amdgcn_s_barrier();
  GCOMP(1);
#undef GSTAGE
#undef GCOMP

#pragma unroll
  for (int i = 0; i < 2; i++) {
#pragma unroll
    for (int j = 0; j < 4; j++) {
      const int mb = m0 + wm * 32 + i * 16 + qd * 4;
      const int n = n0 + wn * 64 + j * 16 + col;
#pragma unroll
      for (int r = 0; r < 4; r++) {
        const int m = mb + r;
        Y[(size_t)m * 1024 + n] = acc[i][j][r] + X[(size_t)m * 1024 + n];
      }
    }
  }

  // ---- fused LayerNorm: last-arriver of the 8 blocks in this row group ----
  __syncthreads();  // all Y stores of this block issued
  __shared__ int lastFlag;
  if (t == 0) {
    __threadfence();  // belt: order Y stores before the release-add
    const int old = __hip_atomic_fetch_add(cnt + blockIdx.x, 1, __ATOMIC_ACQ_REL,
                                           __HIP_MEMORY_SCOPE_AGENT);
    lastFlag = (old == 7) ? 1 : 0;
  }
  __syncthreads();
  if (lastFlag == 0) return;

  // This block LayerNorms rows [m0, m0+64). One wave per 16 rows; each lane
  // owns 16 floats (4x float4) of a row; full-row sum via 6-step shfl_xor.
  float4 g4[4], b4[4];
#pragma unroll
  for (int c = 0; c < 4; ++c) {
    g4[c] = *reinterpret_cast<const float4*>(gamma + c * 256 + lane * 4);
    b4[c] = *reinterpret_cast<const float4*>(beta + c * 256 + lane * 4);
  }
  for (int rr = 0; rr < 16; ++rr) {
    const size_t row = (size_t)m0 + wv * 16 + rr;
    const float* Yr = Y + row * 1024;
    float4 a[4];
#pragma unroll
    for (int c = 0; c < 4; ++c) a[c] = *reinterpret_cast<const float4*>(Yr + c * 256 + lane * 4);
    float s = 0.f, ss = 0.f;
#pragma unroll
    for (int c = 0; c < 4; ++c) {
      s += (a[c].x + a[c].y) + (a[c].z + a[c].w);
      ss += (a[c].x * a[c].x + a[c].y * a[c].y) + (a[c].z * a[c].z + a[c].w * a[c].w);
    }
#pragma unroll
    for (int d = 1; d < 64; d <<= 1) {
      s += __shfl_xor(s, d);
      ss += __shfl_xor(ss, d);
    }
    const float mu = s * (1.f / 1024.f);
    const float var = ss * (1.f / 1024.f) - mu * mu;
    const float rs = rsqrtf(var + 1e-6f);
    float* outr = out + row * 1024;
#pragma unroll
    for (int c = 0; c < 4; ++c) {
      float4 o;
      o.x = (a[c].x - mu) * rs * g4[c].x + b4[c].x;
      o.y = (a[c].y - mu) * rs * g4[c].y + b4[c].y;
      o.z = (a[c].z - mu) * rs * g4[c].z + b4[c].z;
      o.w = (a[c].w - mu) * rs * g4[c].w + b4[c].w;
      *reinterpret_cast<float4*>(outr + c * 256 + lane * 4) = o;
    }
  }
}

// ---------------- flash attention: ring-5, 1 barrier/tile, counted vmcnt, setprio ----------------
// 1D grid (512 blocks) + XCD-chunked swizzle (keeps per-bh K/V L2-resident).
// lsum via MFMA-with-ones B operand (row-sum on the matrix pipe).
__global__ __launch_bounds__(256) void k_attn(const bf16* __restrict__ QB, const bf16* __restrict__ KB,
                                              const bf16* __restrict__ VTB, bf16* __restrict__ OB) {
  __shared__ __align__(16) bf16 Ks[5][64 * 64];  // [buf][perm(kpos)][dk], chunk-swizzled
  __shared__ __align__(16) bf16 Vs[5][64 * 64];  // [buf][dv][kpos], chunk-swizzled
  const int t = threadIdx.x;
  const int lane = t & 63, wv = t >> 6;
  const int qd = lane >> 4, col = lane & 15;
  const int c7 = col & 7;
  const int bid = blockIdx.x;
  const int lin = (bid & 7) * 64 + (bid >> 3);
  const int bh = lin >> 4;
  const int qr = (lin & 15) * 128 + wv * 32;
  const int lrow0 = wv * 8 + (lane >> 3);
  const int scol = ((lane & 7) ^ (lane >> 3)) * 8;  // swizzled source chunk
  // K inverse permutation: LDS row -> kpos (perm: kpos[b4b3|b2|b1b0] -> lds[b2|b4b3|b1b0])
  const int kg0 = ((lrow0 >> 5) << 5) + (((lrow0 >> 2) & 3) << 3) + (((lrow0 >> 4) & 1) << 2) + (lrow0 & 3);
  const int r1 = lrow0 + 32;
  const int kg1 = ((r1 >> 5) << 5) + (((r1 >> 2) & 3) << 3) + (((r1 >> 4) & 1) << 2) + (r1 & 3);
  const bf16* Kg0 = KB + ((size_t)bh * 2048 + kg0) * 64 + scol;
  const bf16* Kg1 = KB + ((size_t)bh * 2048 + kg1) * 64 + scol;
  const bf16* Vg0 = VTB + ((size_t)bh * 64 + lrow0) * 2048 + scol;
  const bf16* Vg1 = VTB + ((size_t)bh * 64 + lrow0 + 32) * 2048 + scol;

  bf16x8 bQ[2][2];
#pragma unroll
  for (int qt = 0; qt < 2; qt++)
#pragma unroll
    for (int s = 0; s < 2; s++)
      bQ[qt][s] = *reinterpret_cast<const bf16x8*>(QB + ((size_t)bh * 2048 + qr + qt * 16 + col) * 64 + s * 32 + qd * 8);

  bf16x8 bOnes;
#pragma unroll
  for (int i = 0; i < 8; i++) bOnes[i] = (bf16)1.0f;

  floatx4 oacc[2][4] = {};
  floatx4 lacc[2] = {};  // lacc[qt][r] = running exp-sum for q-row qd*4+r
  floatx4 scur[2][4];
  int pk[2][4][2];

#define STAGE(bu, ti)                                                  \
  do {                                                                 \
    gll16(Kg0 + (size_t)(ti) * 4096, &Ks[bu][(wv * 8) * 64]);          \
    gll16(Kg1 + (size_t)(ti) * 4096, &Ks[bu][(32 + wv * 8) * 64]);     \
    gll16(Vg0 + (ti) * 64, &Vs[bu][(wv * 8) * 64]);                    \
    gll16(Vg1 + (ti) * 64, &Vs[bu][(32 + wv * 8) * 64]);               \
  } while (0)

#define QK(bu)                                                                                      \
  do {                                                                                              \
    const bf16* ks_ = Ks[bu];                                                                       \
    _Pragma("unroll") for (int nt = 0; nt < 4; nt++) {                                              \
      bf16x8 a0 = *reinterpret_cast<const bf16x8*>(ks_ + (nt * 16 + col) * 64 + (qd ^ c7) * 8);     \
      bf16x8 a1 = *reinterpret_cast<const bf16x8*>(ks_ + (nt * 16 + col) * 64 + ((4 + qd) ^ c7) * 8); \
      _Pragma("unroll") for (int qt = 0; qt < 2; qt++) {                                            \
        floatx4 zz = {0.f, 0.f, 0.f, 0.f};                                                          \
        zz = MFMA16(a0, bQ[qt][0], zz);                                                             \
        zz = MFMA16(a1, bQ[qt][1], zz);                                                             \
        scur[qt][nt] = zz;                                                                          \
      }                                                                                             \
    }                                                                                               \
  } while (0)

#define EXPPACK()                                                                               \
  do {                                                                                          \
    _Pragma("unroll") for (int qt = 0; qt < 2; qt++) {                                          \
      _Pragma("unroll") for (int nt = 0; nt < 4; nt++) {                                        \
        const float e0 = __builtin_amdgcn_exp2f(scur[qt][nt][0]);                               \
        const float e1 = __builtin_amdgcn_exp2f(scur[qt][nt][1]);                               \
        const float e2 = __builtin_amdgcn_exp2f(scur[qt][nt][2]);                               \
        const float e3 = __builtin_amdgcn_exp2f(scur[qt][nt][3]);                               \
        bf16x2 p01, p23;                                                                        \
        p01[0] = (bf16)e0; p01[1] = (bf16)e1;                                                   \
        p23[0] = (bf16)e2; p23[1] = (bf16)e3;                                                   \
        pk[qt][nt][0] = __builtin_bit_cast(int, p01);                                           \
        pk[qt][nt][1] = __builtin_bit_cast(int, p23);                                           \
      }                                                                                         \
    }                                                                                           \
  } while (0)

#define PV(bu)                                                                                      \
  do {                                                                                              \
    const bf16* vs_ = Vs[bu];                                                                       \
    bf16x8 bV[4][2];                                                                                \
    _Pragma("unroll") for (int nd = 0; nd < 4; nd++) {                                              \
      bV[nd][0] = *reinterpret_cast<const bf16x8*>(vs_ + (nd * 16 + col) * 64 + (qd ^ c7) * 8);     \
      bV[nd][1] = *reinterpret_cast<const bf16x8*>(vs_ + (nd * 16 + col) * 64 + ((4 + qd) ^ c7) * 8); \
    }                                                                                               \
    _Pragma("unroll") for (int qt = 0; qt < 2; qt++) {                                              \
      _Pragma("unroll") for (int s = 0; s < 2; s++) {                                               \
        intx4 w;                                                                                    \
        w[0] = pk[qt][2 * s][0]; w[1] = pk[qt][2 * s][1];                                           \
        w[2] = pk[qt][2 * s + 1][0]; w[3] = pk[qt][2 * s + 1][1];                                   \
        const bf16x8 aP = __builtin_bit_cast(bf16x8, w);                                            \
        _Pragma("unroll") for (int nd = 0; nd < 4; nd++)                                            \
          oacc[qt][nd] = MFMA16(aP, bV[nd][s], oacc[qt][nd]);                                       \
        lacc[qt] = MFMA16(aP, bOnes, lacc[qt]);  /* row-sum of exp on matrix pipe */                \
      }                                                                                             \
    }                                                                                               \
  } while (0)

#define ITER5(cur, prv, stg, ti)                                       \
  do {                                                                 \
    asm volatile("s_waitcnt vmcnt(8)" ::: "memory");                   \
    __builtin_amdgcn_s_barrier();                                      \
    STAGE(stg, ((ti) + 3 <= 31) ? ((ti) + 3) : 31);                    \
    EXPPACK();                                                         \
    __builtin_amdgcn_s_setprio(1);                                     \
    QK(cur);                                                           \
    PV(prv);                                                           \
    __builtin_amdgcn_s_setprio(0);                                     \
  } while (0)

  STAGE(0, 0);
  STAGE(1, 1);
  STAGE(2, 2);
  STAGE(3, 3);
  asm volatile("s_waitcnt vmcnt(12)" ::: "memory");
  __builtin_amdgcn_s_barrier();
  QK(0);
  // tiles 1..30: 6 unrolled ring-5 groups
  for (int j = 1; j < 30; j += 5) {
    ITER5(1, 0, 4, j);
    ITER5(2, 1, 0, j + 1);
    ITER5(3, 2, 1, j + 2);
    ITER5(4, 3, 2, j + 3);
    ITER5(0, 4, 3, j + 4);
  }
  ITER5(1, 0, 4, 31);  // tile 31 (buf 1), PV(30) (buf 0)
  EXPPACK();
  __builtin_amdgcn_s_setprio(1);
  PV(1);  // tile 31 lives in buffer 31%5 == 1
  __builtin_amdgcn_s_setprio(0);

  // lane (qd,col) holds full exp-sums for its own rows qd*4+r in lacc[qt][r]
  const int bb = bh >> 4, h = bh & 15;
#pragma unroll
  for (int qt = 0; qt < 2; qt++) {
#pragma unroll
    for (int r = 0; r < 4; r++) {
      const float linv = 1.f / lacc[qt][r];
      const size_t m = (size_t)bb * 2048 + qr + qt * 16 + qd * 4 + r;
#pragma unroll
      for (int nd = 0; nd < 4; nd++)
        OB[m * 1024 + h * 64 + nd * 16 + col] = (bf16)(oacc[qt][nd][r] * linv);
    }
  }
#undef STAGE
#undef QK
#undef EXPPACK
#undef PV
#undef ITER5
}

extern "C" void kernel_launch(void* const* d_in, const int* in_sizes, int n_in,
                              void* d_out, int out_size, void* d_ws, size_t ws_size,
                              hipStream_t stream) {
  (void)in_sizes; (void)n_in; (void)out_size; (void)ws_size;
  const float* x = (const float*)d_in[0];
  const float* Wq = (const float*)d_in[1];
  const float* Wk = (const float*)d_in[2];
  const float* Wv = (const float*)d_in[3];
  const float* Wo = (const float*)d_in[4];
  const float* gamma = (const float*)d_in[5];
  const float* beta = (const float*)d_in[6];

  char* ws = (char*)d_ws;
  const size_t MB = 1ull << 20;
  bf16* XB = (bf16*)(ws);            // 0-8MB (dead after k_gemm<0>)
  bf16* OB = (bf16*)(ws);            // 0-8MB
  bf16* WT = (bf16*)(ws + 8 * MB);   // 8-16MB
  bf16* QB = (bf16*)(ws + 16 * MB);  // 16-24MB
  bf16* KB = (bf16*)(ws + 24 * MB);  // 24-32MB
  bf16* VTB = (bf16*)(ws + 32 * MB); // 32-40MB
  float* Y = (float*)(ws + 40 * MB); // 40-56MB (distinct from QB/KB to keep LN reads clean)
  int* CNT = (int*)(ws + 56 * MB);   // 64 ints: LN row-group counters

  k_prep<<<dim3(32, 32, 8), dim3(32, 8), 0, stream>>>(x, Wq, Wk, Wv, Wo, XB, WT, CNT);
  k_gemm<0><<<dim3(32, 24), 256, 0, stream>>>(XB, WT, nullptr, nullptr, QB, KB, VTB);
  k_attn<<<512, 256, 0, stream>>>(QB, KB, VTB, OB);
  k_gemm_op<<<dim3(64, 8), 256, 0, stream>>>(OB, WT + (size_t)3072 * 1024, x, Y,
                                             gamma, beta, (float*)d_out, CNT);
}

// Round 16
// 185.433 us; speedup vs baseline: 1.2269x; 1.2269x over previous
//
#include <hip/hip_runtime.h>

// B=2, L=2048, D=1024, H=16, DK=DV=64, M=4096.
// R20: REVERT to R18 (best: 186.2us, reproduced 187.3us). R19's last-arriver
//      LN fusion regressed to 227.5 (k_gemm_op 70us): the LN tail ran on 64
//      blocks = 0.25 blocks/CU — parallelism below ~2 blocks/CU is fatal
//      (same lesson as R9/R17). Dedicated 4096-block k_ln restored.
//      Config: 128² ring-2 counted-vmcnt dbuf GEMMs (Wq scale folded at prep),
//      ring-5 attn + XCD swizzle + MFMA-ones lsum + setprio, merged prep.

typedef __bf16 bf16;
typedef __bf16 bf16x2 __attribute__((ext_vector_type(2)));
typedef __bf16 bf16x4 __attribute__((ext_vector_type(4)));
typedef __bf16 bf16x8 __attribute__((ext_vector_type(8)));
typedef float floatx4 __attribute__((ext_vector_type(4)));
typedef int intx4 __attribute__((ext_vector_type(4)));

#define MFMA16(a, b, c) __builtin_amdgcn_mfma_f32_16x16x32_bf16((a), (b), (c), 0, 0, 0)

__device__ __forceinline__ void gll16(const bf16* g, bf16* l) {
  __builtin_amdgcn_global_load_lds((const __attribute__((address_space(1))) void*)g,
                                   (__attribute__((address_space(3))) void*)l, 16, 0, 0);
}

// ---------------- merged prep: z<4 -> transpose W[z] to WT bf16; z>=4 -> x fp32->bf16 ----------------
// z==0 (Wq) rows are pre-scaled by 0.125*log2(e) so the QKV GEMM writes Q directly.
__global__ __launch_bounds__(256) void k_prep(const float* __restrict__ x,
                                              const float* __restrict__ Wq, const float* __restrict__ Wk,
                                              const float* __restrict__ Wv, const float* __restrict__ Wo,
                                              bf16* __restrict__ xb, bf16* __restrict__ WT) {
  __shared__ float tile[32][33];
  const int z = blockIdx.z;
  const int tx = threadIdx.x, ty = threadIdx.y;
  if (z < 4) {
    const float* W = (z == 0) ? Wq : (z == 1) ? Wk : (z == 2) ? Wv : Wo;
    const float sc = (z == 0) ? 0.18033688f : 1.0f;  // 1/8 * log2(e) folded into Wq
    const int n0 = blockIdx.x * 32, k0 = blockIdx.y * 32;
#pragma unroll
    for (int j = 0; j < 32; j += 8)
      tile[ty + j][tx] = W[(size_t)(k0 + ty + j) * 1024 + n0 + tx] * sc;
    __syncthreads();
#pragma unroll
    for (int j = 0; j < 32; j += 8)
      WT[(size_t)(z * 1024 + n0 + ty + j) * 1024 + k0 + tx] = (bf16)tile[tx][ty + j];
  } else {
    // quarter (z-4) of x: 1024 blocks x 256 threads x 4 floats
    const int blin = blockIdx.y * 32 + blockIdx.x;
    const int tid = ty * 32 + tx;
    const size_t i = (((size_t)(z - 4) * 1024 + blin) * 256 + tid) * 4;
    const float4 v = *reinterpret_cast<const float4*>(x + i);
    bf16x4 o = {(bf16)v.x, (bf16)v.y, (bf16)v.z, (bf16)v.w};
    *reinterpret_cast<bf16x4*>(xb + i) = o;
  }
}

// ---------------- QKV GEMM: 128x128, dbuf ring-2 counted vmcnt ----------------
template <int MODE>
__global__ __launch_bounds__(256) void k_gemm(const bf16* __restrict__ A, const bf16* __restrict__ Bt,
                                              const float* __restrict__ X, float* __restrict__ Y,
                                              bf16* __restrict__ QB, bf16* __restrict__ KB,
                                              bf16* __restrict__ VTB) {
  __shared__ __align__(16) bf16 As[2 * 128 * 64];  // slot c^(r&7) holds chunk c of row r
  __shared__ __align__(16) bf16 Bs[2 * 128 * 64];
  const int t = threadIdx.x;
  const int lane = t & 63, wv = t >> 6;
  const int qd = lane >> 4, col = lane & 15;
  const int c7 = col & 7;
  const int wm = wv >> 1, wn = wv & 1;
  const int m0 = blockIdx.x * 128, n0 = blockIdx.y * 128;
  const int srow = wv * 8 + (lane >> 3);
  const int scol = ((lane & 7) ^ (lane >> 3)) * 8;
  const bf16* Ag = A + (size_t)(m0 + srow) * 1024 + scol;
  const bf16* Bg = Bt + (size_t)(n0 + srow) * 1024 + scol;

  floatx4 acc[4][4] = {};

#define GSTAGE(bu, ti)                                                                              \
  do {                                                                                              \
    _Pragma("unroll") for (int rd = 0; rd < 4; rd++) {                                              \
      gll16(Ag + (size_t)rd * 32 * 1024 + (ti) * 64, As + (bu) * 8192 + (rd * 32 + wv * 8) * 64);   \
      gll16(Bg + (size_t)rd * 32 * 1024 + (ti) * 64, Bs + (bu) * 8192 + (rd * 32 + wv * 8) * 64);   \
    }                                                                                               \
  } while (0)

#define GCOMP(bu)                                                                                   \
  do {                                                                                              \
    const bf16* as_ = As + (bu) * 8192;                                                             \
    const bf16* bs_ = Bs + (bu) * 8192;                                                             \
    _Pragma("unroll") for (int ks = 0; ks < 2; ks++) {                                              \
      bf16x8 af[4], bfr[4];                                                                         \
      _Pragma("unroll") for (int i = 0; i < 4; i++)                                                 \
        af[i] = *reinterpret_cast<const bf16x8*>(as_ + (wm * 64 + i * 16 + col) * 64 +              \
                                                 ((ks * 4 + qd) ^ c7) * 8);                         \
      _Pragma("unroll") for (int i = 0; i < 4; i++)                                                 \
        bfr[i] = *reinterpret_cast<const bf16x8*>(bs_ + (wn * 64 + i * 16 + col) * 64 +             \
                                                  ((ks * 4 + qd) ^ c7) * 8);                        \
      _Pragma("unroll") for (int i = 0; i < 4; i++)                                                 \
        _Pragma("unroll") for (int j = 0; j < 4; j++)                                               \
          acc[i][j] = MFMA16(af[i], bfr[j], acc[i][j]);                                             \
    }                                                                                               \
  } while (0)

  // prologue: tiles 0,1 -> bufs 0,1 (16 loads in flight)
  GSTAGE(0, 0);
  GSTAGE(1, 1);
  // steady state, distance-2: vmcnt(8) -> tile t landed (t+1's 8 loads remain
  // in flight); after compute+barrier, refill this buffer with tile t+2.
  for (int ti = 0; ti < 14; ti += 2) {
    asm volatile("s_waitcnt vmcnt(8)" ::: "memory");
    __builtin_amdgcn_s_barrier();
    GCOMP(0);
    __builtin_amdgcn_s_barrier();
    if (ti + 2 < 16) GSTAGE(0, ti + 2);
    asm volatile("s_waitcnt vmcnt(8)" ::: "memory");
    __builtin_amdgcn_s_barrier();
    GCOMP(1);
    __builtin_amdgcn_s_barrier();
    if (ti + 3 < 16) GSTAGE(1, ti + 3);
  }
  // tail: tiles 14 (buf0), 15 (buf1)
  asm volatile("s_waitcnt vmcnt(8)" ::: "memory");
  __builtin_amdgcn_s_barrier();
  GCOMP(0);
  asm volatile("s_waitcnt vmcnt(0)" ::: "memory");
  __builtin_amdgcn_s_barrier();
  GCOMP(1);
#undef GSTAGE
#undef GCOMP

#pragma unroll
  for (int i = 0; i < 4; i++) {
#pragma unroll
    for (int j = 0; j < 4; j++) {
      const int mb = m0 + wm * 64 + i * 16 + qd * 4;
      const int n = n0 + wn * 64 + j * 16 + col;
      if (MODE == 0) {
        const int seg = n >> 10;
        const int h = (n & 1023) >> 6, dd = n & 63;
#pragma unroll
        for (int r = 0; r < 4; r++) {
          const int m = mb + r;
          const int bb = m >> 11, l = m & 2047;
          const float v = acc[i][j][r];
          if (seg == 0)
            QB[((size_t)(bb * 16 + h) * 2048 + l) * 64 + dd] = (bf16)v;  // scale folded into Wq
          else if (seg == 1)
            KB[((size_t)(bb * 16 + h) * 2048 + l) * 64 + dd] = (bf16)v;
          else
            VTB[((size_t)(bb * 16 + h) * 64 + dd) * 2048 + l] = (bf16)v;
        }
      } else {
#pragma unroll
        for (int r = 0; r < 4; r++) {
          const int m = mb + r;
          Y[(size_t)m * 1024 + n] = acc[i][j][r] + X[(size_t)m * 1024 + n];
        }
      }
    }
  }
}

// ---------------- output projection: 64x128 tile, 512 blocks, ring-2 counted vmcnt ----------------
// Y = OB * Wo^T + x. 4 waves as 2m x 2n; wave tile 32x64 (acc[2][4]).
__global__ __launch_bounds__(256) void k_gemm_op(const bf16* __restrict__ A, const bf16* __restrict__ Bt,
                                                 const float* __restrict__ X, float* __restrict__ Y) {
  __shared__ __align__(16) bf16 As[2 * 64 * 64];   // slot c^(r&7) holds chunk c of row r
  __shared__ __align__(16) bf16 Bs[2 * 128 * 64];
  const int t = threadIdx.x;
  const int lane = t & 63, wv = t >> 6;
  const int qd = lane >> 4, col = lane & 15;
  const int c7 = col & 7;
  const int wm = wv >> 1, wn = wv & 1;
  const int m0 = blockIdx.x * 64, n0 = blockIdx.y * 128;
  const int srow = wv * 8 + (lane >> 3);           // 0..31
  const int scol = ((lane & 7) ^ (lane >> 3)) * 8;
  const bf16* Ag = A + (size_t)(m0 + srow) * 1024 + scol;
  const bf16* Bg = Bt + (size_t)(n0 + srow) * 1024 + scol;

  floatx4 acc[2][4] = {};

#define GSTAGE(bu, ti)                                                                              \
  do {                                                                                              \
    _Pragma("unroll") for (int rd = 0; rd < 2; rd++)                                                \
      gll16(Ag + (size_t)rd * 32 * 1024 + (ti) * 64, As + (bu) * 4096 + (rd * 32 + wv * 8) * 64);   \
    _Pragma("unroll") for (int rd = 0; rd < 4; rd++)                                                \
      gll16(Bg + (size_t)rd * 32 * 1024 + (ti) * 64, Bs + (bu) * 8192 + (rd * 32 + wv * 8) * 64);   \
  } while (0)

#define GCOMP(bu)                                                                                   \
  do {                                                                                              \
    const bf16* as_ = As + (bu) * 4096;                                                             \
    const bf16* bs_ = Bs + (bu) * 8192;                                                             \
    _Pragma("unroll") for (int ks = 0; ks < 2; ks++) {                                              \
      bf16x8 af[2], bfr[4];                                                                         \
      _Pragma("unroll") for (int i = 0; i < 2; i++)                                                 \
        af[i] = *reinterpret_cast<const bf16x8*>(as_ + (wm * 32 + i * 16 + col) * 64 +              \
                                                 ((ks * 4 + qd) ^ c7) * 8);                         \
      _Pragma("unroll") for (int j = 0; j < 4; j++)                                                 \
        bfr[j] = *reinterpret_cast<const bf16x8*>(bs_ + (wn * 64 + j * 16 + col) * 64 +             \
                                                  ((ks * 4 + qd) ^ c7) * 8);                        \
      _Pragma("unroll") for (int i = 0; i < 2; i++)                                                 \
        _Pragma("unroll") for (int j = 0; j < 4; j++)                                               \
          acc[i][j] = MFMA16(af[i], bfr[j], acc[i][j]);                                             \
    }                                                                                               \
  } while (0)

  // prologue: tiles 0,1 (6 loads each; 12 in flight)
  GSTAGE(0, 0);
  GSTAGE(1, 1);
  for (int ti = 0; ti < 14; ti += 2) {
    asm volatile("s_waitcnt vmcnt(6)" ::: "memory");
    __builtin_amdgcn_s_barrier();
    GCOMP(0);
    __builtin_amdgcn_s_barrier();
    if (ti + 2 < 16) GSTAGE(0, ti + 2);
    asm volatile("s_waitcnt vmcnt(6)" ::: "memory");
    __builtin_amdgcn_s_barrier();
    GCOMP(1);
    __builtin_amdgcn_s_barrier();
    if (ti + 3 < 16) GSTAGE(1, ti + 3);
  }
  asm volatile("s_waitcnt vmcnt(6)" ::: "memory");
  __builtin_amdgcn_s_barrier();
  GCOMP(0);
  asm volatile("s_waitcnt vmcnt(0)" ::: "memory");
  __builtin_amdgcn_s_barrier();
  GCOMP(1);
#undef GSTAGE
#undef GCOMP

#pragma unroll
  for (int i = 0; i < 2; i++) {
#pragma unroll
    for (int j = 0; j < 4; j++) {
      const int mb = m0 + wm * 32 + i * 16 + qd * 4;
      const int n = n0 + wn * 64 + j * 16 + col;
#pragma unroll
      for (int r = 0; r < 4; r++) {
        const int m = mb + r;
        Y[(size_t)m * 1024 + n] = acc[i][j][r] + X[(size_t)m * 1024 + n];
      }
    }
  }
}

// ---------------- flash attention: ring-5, 1 barrier/tile, counted vmcnt, setprio ----------------
// 1D grid (512 blocks) + XCD-chunked swizzle (keeps per-bh K/V L2-resident).
// lsum via MFMA-with-ones B operand (row-sum on the matrix pipe).
__global__ __launch_bounds__(256) void k_attn(const bf16* __restrict__ QB, const bf16* __restrict__ KB,
                                              const bf16* __restrict__ VTB, bf16* __restrict__ OB) {
  __shared__ __align__(16) bf16 Ks[5][64 * 64];  // [buf][perm(kpos)][dk], chunk-swizzled
  __shared__ __align__(16) bf16 Vs[5][64 * 64];  // [buf][dv][kpos], chunk-swizzled
  const int t = threadIdx.x;
  const int lane = t & 63, wv = t >> 6;
  const int qd = lane >> 4, col = lane & 15;
  const int c7 = col & 7;
  const int bid = blockIdx.x;
  const int lin = (bid & 7) * 64 + (bid >> 3);
  const int bh = lin >> 4;
  const int qr = (lin & 15) * 128 + wv * 32;
  const int lrow0 = wv * 8 + (lane >> 3);
  const int scol = ((lane & 7) ^ (lane >> 3)) * 8;  // swizzled source chunk
  // K inverse permutation: LDS row -> kpos (perm: kpos[b4b3|b2|b1b0] -> lds[b2|b4b3|b1b0])
  const int kg0 = ((lrow0 >> 5) << 5) + (((lrow0 >> 2) & 3) << 3) + (((lrow0 >> 4) & 1) << 2) + (lrow0 & 3);
  const int r1 = lrow0 + 32;
  const int kg1 = ((r1 >> 5) << 5) + (((r1 >> 2) & 3) << 3) + (((r1 >> 4) & 1) << 2) + (r1 & 3);
  const bf16* Kg0 = KB + ((size_t)bh * 2048 + kg0) * 64 + scol;
  const bf16* Kg1 = KB + ((size_t)bh * 2048 + kg1) * 64 + scol;
  const bf16* Vg0 = VTB + ((size_t)bh * 64 + lrow0) * 2048 + scol;
  const bf16* Vg1 = VTB + ((size_t)bh * 64 + lrow0 + 32) * 2048 + scol;

  bf16x8 bQ[2][2];
#pragma unroll
  for (int qt = 0; qt < 2; qt++)
#pragma unroll
    for (int s = 0; s < 2; s++)
      bQ[qt][s] = *reinterpret_cast<const bf16x8*>(QB + ((size_t)bh * 2048 + qr + qt * 16 + col) * 64 + s * 32 + qd * 8);

  bf16x8 bOnes;
#pragma unroll
  for (int i = 0; i < 8; i++) bOnes[i] = (bf16)1.0f;

  floatx4 oacc[2][4] = {};
  floatx4 lacc[2] = {};  // lacc[qt][r] = running exp-sum for q-row qd*4+r
  floatx4 scur[2][4];
  int pk[2][4][2];

#define STAGE(bu, ti)                                                  \
  do {                                                                 \
    gll16(Kg0 + (size_t)(ti) * 4096, &Ks[bu][(wv * 8) * 64]);          \
    gll16(Kg1 + (size_t)(ti) * 4096, &Ks[bu][(32 + wv * 8) * 64]);     \
    gll16(Vg0 + (ti) * 64, &Vs[bu][(wv * 8) * 64]);                    \
    gll16(Vg1 + (ti) * 64, &Vs[bu][(32 + wv * 8) * 64]);               \
  } while (0)

#define QK(bu)                                                                                      \
  do {                                                                                              \
    const bf16* ks_ = Ks[bu];                                                                       \
    _Pragma("unroll") for (int nt = 0; nt < 4; nt++) {                                              \
      bf16x8 a0 = *reinterpret_cast<const bf16x8*>(ks_ + (nt * 16 + col) * 64 + (qd ^ c7) * 8);     \
      bf16x8 a1 = *reinterpret_cast<const bf16x8*>(ks_ + (nt * 16 + col) * 64 + ((4 + qd) ^ c7) * 8); \
      _Pragma("unroll") for (int qt = 0; qt < 2; qt++) {                                            \
        floatx4 zz = {0.f, 0.f, 0.f, 0.f};                                                          \
        zz = MFMA16(a0, bQ[qt][0], zz);                                                             \
        zz = MFMA16(a1, bQ[qt][1], zz);                                                             \
        scur[qt][nt] = zz;                                                                          \
      }                                                                                             \
    }                                                                                               \
  } while (0)

#define EXPPACK()                                                                               \
  do {                                                                                          \
    _Pragma("unroll") for (int qt = 0; qt < 2; qt++) {                                          \
      _Pragma("unroll") for (int nt = 0; nt < 4; nt++) {                                        \
        const float e0 = __builtin_amdgcn_exp2f(scur[qt][nt][0]);                               \
        const float e1 = __builtin_amdgcn_exp2f(scur[qt][nt][1]);                               \
        const float e2 = __builtin_amdgcn_exp2f(scur[qt][nt][2]);                               \
        const float e3 = __builtin_amdgcn_exp2f(scur[qt][nt][3]);                               \
        bf16x2 p01, p23;                                                                        \
        p01[0] = (bf16)e0; p01[1] = (bf16)e1;                                                   \
        p23[0] = (bf16)e2; p23[1] = (bf16)e3;                                                   \
        pk[qt][nt][0] = __builtin_bit_cast(int, p01);                                           \
        pk[qt][nt][1] = __builtin_bit_cast(int, p23);                                           \
      }                                                                                         \
    }                                                                                           \
  } while (0)

#define PV(bu)                                                                                      \
  do {                                                                                              \
    const bf16* vs_ = Vs[bu];                                                                       \
    bf16x8 bV[4][2];                                                                                \
    _Pragma("unroll") for (int nd = 0; nd < 4; nd++) {                                              \
      bV[nd][0] = *reinterpret_cast<const bf16x8*>(vs_ + (nd * 16 + col) * 64 + (qd ^ c7) * 8);     \
      bV[nd][1] = *reinterpret_cast<const bf16x8*>(vs_ + (nd * 16 + col) * 64 + ((4 + qd) ^ c7) * 8); \
    }                                                                                               \
    _Pragma("unroll") for (int qt = 0; qt < 2; qt++) {                                              \
      _Pragma("unroll") for (int s = 0; s < 2; s++) {                                               \
        intx4 w;                                                                                    \
        w[0] = pk[qt][2 * s][0]; w[1] = pk[qt][2 * s][1];                                           \
        w[2] = pk[qt][2 * s + 1][0]; w[3] = pk[qt][2 * s + 1][1];                                   \
        const bf16x8 aP = __builtin_bit_cast(bf16x8, w);                                            \
        _Pragma("unroll") for (int nd = 0; nd < 4; nd++)                                            \
          oacc[qt][nd] = MFMA16(aP, bV[nd][s], oacc[qt][nd]);                                       \
        lacc[qt] = MFMA16(aP, bOnes, lacc[qt]);  /* row-sum of exp on matrix pipe */                \
      }                                                                                             \
    }                                                                                               \
  } while (0)

#define ITER5(cur, prv, stg, ti)                                       \
  do {                                                                 \
    asm volatile("s_waitcnt vmcnt(8)" ::: "memory");                   \
    __builtin_amdgcn_s_barrier();                                      \
    STAGE(stg, ((ti) + 3 <= 31) ? ((ti) + 3) : 31);                    \
    EXPPACK();                                                         \
    __builtin_amdgcn_s_setprio(1);                                     \
    QK(cur);                                                           \
    PV(prv);                                                           \
    __builtin_amdgcn_s_setprio(0);                                     \
  } while (0)

  STAGE(0, 0);
  STAGE(1, 1);
  STAGE(2, 2);
  STAGE(3, 3);
  asm volatile("s_waitcnt vmcnt(12)" ::: "memory");
  __builtin_amdgcn_s_barrier();
  QK(0);
  // tiles 1..30: 6 unrolled ring-5 groups
  for (int j = 1; j < 30; j += 5) {
    ITER5(1, 0, 4, j);
    ITER5(2, 1, 0, j + 1);
    ITER5(3, 2, 1, j + 2);
    ITER5(4, 3, 2, j + 3);
    ITER5(0, 4, 3, j + 4);
  }
  ITER5(1, 0, 4, 31);  // tile 31 (buf 1), PV(30) (buf 0)
  EXPPACK();
  __builtin_amdgcn_s_setprio(1);
  PV(1);  // tile 31 lives in buffer 31%5 == 1
  __builtin_amdgcn_s_setprio(0);

  // lane (qd,col) holds full exp-sums for its own rows qd*4+r in lacc[qt][r]
  const int bb = bh >> 4, h = bh & 15;
#pragma unroll
  for (int qt = 0; qt < 2; qt++) {
#pragma unroll
    for (int r = 0; r < 4; r++) {
      const float linv = 1.f / lacc[qt][r];
      const size_t m = (size_t)bb * 2048 + qr + qt * 16 + qd * 4 + r;
#pragma unroll
      for (int nd = 0; nd < 4; nd++)
        OB[m * 1024 + h * 64 + nd * 16 + col] = (bf16)(oacc[qt][nd][r] * linv);
    }
  }
#undef STAGE
#undef QK
#undef EXPPACK
#undef PV
#undef ITER5
}

// ---------------- LayerNorm ----------------
__global__ __launch_bounds__(256) void k_ln(const float* __restrict__ Yin, const float* __restrict__ gamma,
                                            const float* __restrict__ beta, float* __restrict__ out) {
  __shared__ float red[8];
  const int row = blockIdx.x, t = threadIdx.x;
  const float4 v = *reinterpret_cast<const float4*>(Yin + (size_t)row * 1024 + t * 4);
  float s = v.x + v.y + v.z + v.w;
  float ss = v.x * v.x + v.y * v.y + v.z * v.z + v.w * v.w;
#pragma unroll
  for (int d = 1; d < 64; d <<= 1) {
    s += __shfl_xor(s, d);
    ss += __shfl_xor(ss, d);
  }
  if ((t & 63) == 0) {
    red[t >> 6] = s;
    red[4 + (t >> 6)] = ss;
  }
  __syncthreads();
  s = red[0] + red[1] + red[2] + red[3];
  ss = red[4] + red[5] + red[6] + red[7];
  const float mu = s * (1.f / 1024.f);
  const float var = ss * (1.f / 1024.f) - mu * mu;
  const float rs = rsqrtf(var + 1e-6f);
  const float4 g = *reinterpret_cast<const float4*>(gamma + t * 4);
  const float4 bt = *reinterpret_cast<const float4*>(beta + t * 4);
  float4 o;
  o.x = (v.x - mu) * rs * g.x + bt.x;
  o.y = (v.y - mu) * rs * g.y + bt.y;
  o.z = (v.z - mu) * rs * g.z + bt.z;
  o.w = (v.w - mu) * rs * g.w + bt.w;
  *reinterpret_cast<float4*>(out + (size_t)row * 1024 + t * 4) = o;
}

extern "C" void kernel_launch(void* const* d_in, const int* in_sizes, int n_in,
                              void* d_out, int out_size, void* d_ws, size_t ws_size,
                              hipStream_t stream) {
  (void)in_sizes; (void)n_in; (void)out_size; (void)ws_size;
  const float* x = (const float*)d_in[0];
  const float* Wq = (const float*)d_in[1];
  const float* Wk = (const float*)d_in[2];
  const float* Wv = (const float*)d_in[3];
  const float* Wo = (const float*)d_in[4];
  const float* gamma = (const float*)d_in[5];
  const float* beta = (const float*)d_in[6];

  char* ws = (char*)d_ws;
  const size_t MB = 1ull << 20;
  bf16* XB = (bf16*)(ws);            // 0-8MB (dead after k_gemm<0>)
  bf16* OB = (bf16*)(ws);            // 0-8MB
  bf16* WT = (bf16*)(ws + 8 * MB);   // 8-16MB
  bf16* QB = (bf16*)(ws + 16 * MB);  // 16-24MB
  bf16* KB = (bf16*)(ws + 24 * MB);  // 24-32MB
  bf16* VTB = (bf16*)(ws + 32 * MB); // 32-40MB
  float* Y = (float*)(ws + 16 * MB); // reuses QB/KB region after attn consumed them

  k_prep<<<dim3(32, 32, 8), dim3(32, 8), 0, stream>>>(x, Wq, Wk, Wv, Wo, XB, WT);
  k_gemm<0><<<dim3(32, 24), 256, 0, stream>>>(XB, WT, nullptr, nullptr, QB, KB, VTB);
  k_attn<<<512, 256, 0, stream>>>(QB, KB, VTB, OB);
  k_gemm_op<<<dim3(64, 8), 256, 0, stream>>>(OB, WT + (size_t)3072 * 1024, x, Y);
  k_ln<<<4096, 256, 0, stream>>>(Y, gamma, beta, (float*)d_out);
}

// Round 17
// 185.023 us; speedup vs baseline: 1.2297x; 1.0022x over previous
//
#include <hip/hip_runtime.h>

// B=2, L=2048, D=1024, H=16, DK=DV=64, M=4096.
// R21: k_gemm<0> BK 64->32 (LDS 64->32KB): 2 -> 4 blocks/CU, all 768 blocks
//      co-resident (no residency tail), 2x independent blocks to hide the
//      per-step vmcnt/barrier drain. Same ring-2 counted-vmcnt topology,
//      same wave tile, swizzle re-derived for 4-chunk rows (slot=qd^(col&3),
//      2-way banks = free). Everything else frozen at R20 (best 185.4us).

typedef __bf16 bf16;
typedef __bf16 bf16x2 __attribute__((ext_vector_type(2)));
typedef __bf16 bf16x4 __attribute__((ext_vector_type(4)));
typedef __bf16 bf16x8 __attribute__((ext_vector_type(8)));
typedef float floatx4 __attribute__((ext_vector_type(4)));
typedef int intx4 __attribute__((ext_vector_type(4)));

#define MFMA16(a, b, c) __builtin_amdgcn_mfma_f32_16x16x32_bf16((a), (b), (c), 0, 0, 0)

__device__ __forceinline__ void gll16(const bf16* g, bf16* l) {
  __builtin_amdgcn_global_load_lds((const __attribute__((address_space(1))) void*)g,
                                   (__attribute__((address_space(3))) void*)l, 16, 0, 0);
}

// ---------------- merged prep: z<4 -> transpose W[z] to WT bf16; z>=4 -> x fp32->bf16 ----------------
// z==0 (Wq) rows are pre-scaled by 0.125*log2(e) so the QKV GEMM writes Q directly.
__global__ __launch_bounds__(256) void k_prep(const float* __restrict__ x,
                                              const float* __restrict__ Wq, const float* __restrict__ Wk,
                                              const float* __restrict__ Wv, const float* __restrict__ Wo,
                                              bf16* __restrict__ xb, bf16* __restrict__ WT) {
  __shared__ float tile[32][33];
  const int z = blockIdx.z;
  const int tx = threadIdx.x, ty = threadIdx.y;
  if (z < 4) {
    const float* W = (z == 0) ? Wq : (z == 1) ? Wk : (z == 2) ? Wv : Wo;
    const float sc = (z == 0) ? 0.18033688f : 1.0f;  // 1/8 * log2(e) folded into Wq
    const int n0 = blockIdx.x * 32, k0 = blockIdx.y * 32;
#pragma unroll
    for (int j = 0; j < 32; j += 8)
      tile[ty + j][tx] = W[(size_t)(k0 + ty + j) * 1024 + n0 + tx] * sc;
    __syncthreads();
#pragma unroll
    for (int j = 0; j < 32; j += 8)
      WT[(size_t)(z * 1024 + n0 + ty + j) * 1024 + k0 + tx] = (bf16)tile[tx][ty + j];
  } else {
    // quarter (z-4) of x: 1024 blocks x 256 threads x 4 floats
    const int blin = blockIdx.y * 32 + blockIdx.x;
    const int tid = ty * 32 + tx;
    const size_t i = (((size_t)(z - 4) * 1024 + blin) * 256 + tid) * 4;
    const float4 v = *reinterpret_cast<const float4*>(x + i);
    bf16x4 o = {(bf16)v.x, (bf16)v.y, (bf16)v.z, (bf16)v.w};
    *reinterpret_cast<bf16x4*>(xb + i) = o;
  }
}

// ---------------- QKV GEMM: 128x128, BK=32, dbuf ring-2 counted vmcnt, 4 blocks/CU ----------------
// LDS row = 32 bf16 (64B) = 4 chunks of 16B; slot s of row r holds chunk s^(r&3).
template <int MODE>
__global__ __launch_bounds__(256) void k_gemm(const bf16* __restrict__ A, const bf16* __restrict__ Bt,
                                              const float* __restrict__ X, float* __restrict__ Y,
                                              bf16* __restrict__ QB, bf16* __restrict__ KB,
                                              bf16* __restrict__ VTB) {
  __shared__ __align__(16) bf16 As[2 * 128 * 32];  // 2 bufs x 128 rows x 32 cols (16KB)
  __shared__ __align__(16) bf16 Bs[2 * 128 * 32];
  const int t = threadIdx.x;
  const int lane = t & 63, wv = t >> 6;
  const int qd = lane >> 4, col = lane & 15;
  const int c3 = col & 3;
  const int wm = wv >> 1, wn = wv & 1;
  const int m0 = blockIdx.x * 128, n0 = blockIdx.y * 128;
  // staging: wave wv covers 16 rows per line; lane l -> row base+(l>>2), slot l&3,
  // source chunk (l&3)^((l>>2)&3)
  const int srow = wv * 16 + (lane >> 2);
  const int scol = ((lane & 3) ^ ((lane >> 2) & 3)) * 8;
  const bf16* Ag = A + (size_t)(m0 + srow) * 1024 + scol;
  const bf16* Bg = Bt + (size_t)(n0 + srow) * 1024 + scol;

  floatx4 acc[4][4] = {};

#define GSTAGE(bu, ti)                                                                              \
  do {                                                                                              \
    _Pragma("unroll") for (int rd = 0; rd < 2; rd++) {                                              \
      gll16(Ag + (size_t)rd * 64 * 1024 + (ti) * 32, As + (bu) * 4096 + (rd * 64 + wv * 16) * 32);  \
      gll16(Bg + (size_t)rd * 64 * 1024 + (ti) * 32, Bs + (bu) * 4096 + (rd * 64 + wv * 16) * 32);  \
    }                                                                                               \
  } while (0)

#define GCOMP(bu)                                                                                   \
  do {                                                                                              \
    const bf16* as_ = As + (bu) * 4096;                                                             \
    const bf16* bs_ = Bs + (bu) * 4096;                                                             \
    bf16x8 af[4], bfr[4];                                                                           \
    _Pragma("unroll") for (int i = 0; i < 4; i++)                                                   \
      af[i] = *reinterpret_cast<const bf16x8*>(as_ + (wm * 64 + i * 16 + col) * 32 +                \
                                               ((qd ^ c3) * 8));                                    \
    _Pragma("unroll") for (int j = 0; j < 4; j++)                                                   \
      bfr[j] = *reinterpret_cast<const bf16x8*>(bs_ + (wn * 64 + j * 16 + col) * 32 +               \
                                                ((qd ^ c3) * 8));                                   \
    _Pragma("unroll") for (int i = 0; i < 4; i++)                                                   \
      _Pragma("unroll") for (int j = 0; j < 4; j++)                                                 \
        acc[i][j] = MFMA16(af[i], bfr[j], acc[i][j]);                                               \
  } while (0)

  // prologue: K-tiles 0,1 -> bufs 0,1 (8 loads/wave in flight)
  GSTAGE(0, 0);
  GSTAGE(1, 1);
  // steady state, distance-2: vmcnt(4) -> tile t landed (t+1's 4 loads remain
  // in flight); after compute+barrier, refill this buffer with tile t+2.
  for (int ti = 0; ti < 30; ti += 2) {
    asm volatile("s_waitcnt vmcnt(4)" ::: "memory");
    __builtin_amdgcn_s_barrier();
    GCOMP(0);
    __builtin_amdgcn_s_barrier();
    if (ti + 2 < 32) GSTAGE(0, ti + 2);
    asm volatile("s_waitcnt vmcnt(4)" ::: "memory");
    __builtin_amdgcn_s_barrier();
    GCOMP(1);
    __builtin_amdgcn_s_barrier();
    if (ti + 3 < 32) GSTAGE(1, ti + 3);
  }
  // tail: K-tiles 30 (buf0), 31 (buf1)
  asm volatile("s_waitcnt vmcnt(4)" ::: "memory");
  __builtin_amdgcn_s_barrier();
  GCOMP(0);
  asm volatile("s_waitcnt vmcnt(0)" ::: "memory");
  __builtin_amdgcn_s_barrier();
  GCOMP(1);
#undef GSTAGE
#undef GCOMP

#pragma unroll
  for (int i = 0; i < 4; i++) {
#pragma unroll
    for (int j = 0; j < 4; j++) {
      const int mb = m0 + wm * 64 + i * 16 + qd * 4;
      const int n = n0 + wn * 64 + j * 16 + col;
      if (MODE == 0) {
        const int seg = n >> 10;
        const int h = (n & 1023) >> 6, dd = n & 63;
#pragma unroll
        for (int r = 0; r < 4; r++) {
          const int m = mb + r;
          const int bb = m >> 11, l = m & 2047;
          const float v = acc[i][j][r];
          if (seg == 0)
            QB[((size_t)(bb * 16 + h) * 2048 + l) * 64 + dd] = (bf16)v;  // scale folded into Wq
          else if (seg == 1)
            KB[((size_t)(bb * 16 + h) * 2048 + l) * 64 + dd] = (bf16)v;
          else
            VTB[((size_t)(bb * 16 + h) * 64 + dd) * 2048 + l] = (bf16)v;
        }
      } else {
#pragma unroll
        for (int r = 0; r < 4; r++) {
          const int m = mb + r;
          Y[(size_t)m * 1024 + n] = acc[i][j][r] + X[(size_t)m * 1024 + n];
        }
      }
    }
  }
}

// ---------------- output projection: 64x128 tile, 512 blocks, ring-2 counted vmcnt ----------------
// Y = OB * Wo^T + x. 4 waves as 2m x 2n; wave tile 32x64 (acc[2][4]).
__global__ __launch_bounds__(256) void k_gemm_op(const bf16* __restrict__ A, const bf16* __restrict__ Bt,
                                                 const float* __restrict__ X, float* __restrict__ Y) {
  __shared__ __align__(16) bf16 As[2 * 64 * 64];   // slot c^(r&7) holds chunk c of row r
  __shared__ __align__(16) bf16 Bs[2 * 128 * 64];
  const int t = threadIdx.x;
  const int lane = t & 63, wv = t >> 6;
  const int qd = lane >> 4, col = lane & 15;
  const int c7 = col & 7;
  const int wm = wv >> 1, wn = wv & 1;
  const int m0 = blockIdx.x * 64, n0 = blockIdx.y * 128;
  const int srow = wv * 8 + (lane >> 3);           // 0..31
  const int scol = ((lane & 7) ^ (lane >> 3)) * 8;
  const bf16* Ag = A + (size_t)(m0 + srow) * 1024 + scol;
  const bf16* Bg = Bt + (size_t)(n0 + srow) * 1024 + scol;

  floatx4 acc[2][4] = {};

#define GSTAGE(bu, ti)                                                                              \
  do {                                                                                              \
    _Pragma("unroll") for (int rd = 0; rd < 2; rd++)                                                \
      gll16(Ag + (size_t)rd * 32 * 1024 + (ti) * 64, As + (bu) * 4096 + (rd * 32 + wv * 8) * 64);   \
    _Pragma("unroll") for (int rd = 0; rd < 4; rd++)                                                \
      gll16(Bg + (size_t)rd * 32 * 1024 + (ti) * 64, Bs + (bu) * 8192 + (rd * 32 + wv * 8) * 64);   \
  } while (0)

#define GCOMP(bu)                                                                                   \
  do {                                                                                              \
    const bf16* as_ = As + (bu) * 4096;                                                             \
    const bf16* bs_ = Bs + (bu) * 8192;                                                             \
    _Pragma("unroll") for (int ks = 0; ks < 2; ks++) {                                              \
      bf16x8 af[2], bfr[4];                                                                         \
      _Pragma("unroll") for (int i = 0; i < 2; i++)                                                 \
        af[i] = *reinterpret_cast<const bf16x8*>(as_ + (wm * 32 + i * 16 + col) * 64 +              \
                                                 ((ks * 4 + qd) ^ c7) * 8);                         \
      _Pragma("unroll") for (int j = 0; j < 4; j++)                                                 \
        bfr[j] = *reinterpret_cast<const bf16x8*>(bs_ + (wn * 64 + j * 16 + col) * 64 +             \
                                                  ((ks * 4 + qd) ^ c7) * 8);                        \
      _Pragma("unroll") for (int i = 0; i < 2; i++)                                                 \
        _Pragma("unroll") for (int j = 0; j < 4; j++)                                               \
          acc[i][j] = MFMA16(af[i], bfr[j], acc[i][j]);                                             \
    }                                                                                               \
  } while (0)

  // prologue: tiles 0,1 (6 loads each; 12 in flight)
  GSTAGE(0, 0);
  GSTAGE(1, 1);
  for (int ti = 0; ti < 14; ti += 2) {
    asm volatile("s_waitcnt vmcnt(6)" ::: "memory");
    __builtin_amdgcn_s_barrier();
    GCOMP(0);
    __builtin_amdgcn_s_barrier();
    if (ti + 2 < 16) GSTAGE(0, ti + 2);
    asm volatile("s_waitcnt vmcnt(6)" ::: "memory");
    __builtin_amdgcn_s_barrier();
    GCOMP(1);
    __builtin_amdgcn_s_barrier();
    if (ti + 3 < 16) GSTAGE(1, ti + 3);
  }
  asm volatile("s_waitcnt vmcnt(6)" ::: "memory");
  __builtin_amdgcn_s_barrier();
  GCOMP(0);
  asm volatile("s_waitcnt vmcnt(0)" ::: "memory");
  __builtin_amdgcn_s_barrier();
  GCOMP(1);
#undef GSTAGE
#undef GCOMP

#pragma unroll
  for (int i = 0; i < 2; i++) {
#pragma unroll
    for (int j = 0; j < 4; j++) {
      const int mb = m0 + wm * 32 + i * 16 + qd * 4;
      const int n = n0 + wn * 64 + j * 16 + col;
#pragma unroll
      for (int r = 0; r < 4; r++) {
        const int m = mb + r;
        Y[(size_t)m * 1024 + n] = acc[i][j][r] + X[(size_t)m * 1024 + n];
      }
    }
  }
}

// ---------------- flash attention: ring-5, 1 barrier/tile, counted vmcnt, setprio ----------------
// 1D grid (512 blocks) + XCD-chunked swizzle (keeps per-bh K/V L2-resident).
// lsum via MFMA-with-ones B operand (row-sum on the matrix pipe).
__global__ __launch_bounds__(256) void k_attn(const bf16* __restrict__ QB, const bf16* __restrict__ KB,
                                              const bf16* __restrict__ VTB, bf16* __restrict__ OB) {
  __shared__ __align__(16) bf16 Ks[5][64 * 64];  // [buf][perm(kpos)][dk], chunk-swizzled
  __shared__ __align__(16) bf16 Vs[5][64 * 64];  // [buf][dv][kpos], chunk-swizzled
  const int t = threadIdx.x;
  const int lane = t & 63, wv = t >> 6;
  const int qd = lane >> 4, col = lane & 15;
  const int c7 = col & 7;
  const int bid = blockIdx.x;
  const int lin = (bid & 7) * 64 + (bid >> 3);
  const int bh = lin >> 4;
  const int qr = (lin & 15) * 128 + wv * 32;
  const int lrow0 = wv * 8 + (lane >> 3);
  const int scol = ((lane & 7) ^ (lane >> 3)) * 8;  // swizzled source chunk
  // K inverse permutation: LDS row -> kpos (perm: kpos[b4b3|b2|b1b0] -> lds[b2|b4b3|b1b0])
  const int kg0 = ((lrow0 >> 5) << 5) + (((lrow0 >> 2) & 3) << 3) + (((lrow0 >> 4) & 1) << 2) + (lrow0 & 3);
  const int r1 = lrow0 + 32;
  const int kg1 = ((r1 >> 5) << 5) + (((r1 >> 2) & 3) << 3) + (((r1 >> 4) & 1) << 2) + (r1 & 3);
  const bf16* Kg0 = KB + ((size_t)bh * 2048 + kg0) * 64 + scol;
  const bf16* Kg1 = KB + ((size_t)bh * 2048 + kg1) * 64 + scol;
  const bf16* Vg0 = VTB + ((size_t)bh * 64 + lrow0) * 2048 + scol;
  const bf16* Vg1 = VTB + ((size_t)bh * 64 + lrow0 + 32) * 2048 + scol;

  bf16x8 bQ[2][2];
#pragma unroll
  for (int qt = 0; qt < 2; qt++)
#pragma unroll
    for (int s = 0; s < 2; s++)
      bQ[qt][s] = *reinterpret_cast<const bf16x8*>(QB + ((size_t)bh * 2048 + qr + qt * 16 + col) * 64 + s * 32 + qd * 8);

  bf16x8 bOnes;
#pragma unroll
  for (int i = 0; i < 8; i++) bOnes[i] = (bf16)1.0f;

  floatx4 oacc[2][4] = {};
  floatx4 lacc[2] = {};  // lacc[qt][r] = running exp-sum for q-row qd*4+r
  floatx4 scur[2][4];
  int pk[2][4][2];

#define STAGE(bu, ti)                                                  \
  do {                                                                 \
    gll16(Kg0 + (size_t)(ti) * 4096, &Ks[bu][(wv * 8) * 64]);          \
    gll16(Kg1 + (size_t)(ti) * 4096, &Ks[bu][(32 + wv * 8) * 64]);     \
    gll16(Vg0 + (ti) * 64, &Vs[bu][(wv * 8) * 64]);                    \
    gll16(Vg1 + (ti) * 64, &Vs[bu][(32 + wv * 8) * 64]);               \
  } while (0)

#define QK(bu)                                                                                      \
  do {                                                                                              \
    const bf16* ks_ = Ks[bu];                                                                       \
    _Pragma("unroll") for (int nt = 0; nt < 4; nt++) {                                              \
      bf16x8 a0 = *reinterpret_cast<const bf16x8*>(ks_ + (nt * 16 + col) * 64 + (qd ^ c7) * 8);     \
      bf16x8 a1 = *reinterpret_cast<const bf16x8*>(ks_ + (nt * 16 + col) * 64 + ((4 + qd) ^ c7) * 8); \
      _Pragma("unroll") for (int qt = 0; qt < 2; qt++) {                                            \
        floatx4 zz = {0.f, 0.f, 0.f, 0.f};                                                          \
        zz = MFMA16(a0, bQ[qt][0], zz);                                                             \
        zz = MFMA16(a1, bQ[qt][1], zz);                                                             \
        scur[qt][nt] = zz;                                                                          \
      }                                                                                             \
    }                                                                                               \
  } while (0)

#define EXPPACK()                                                                               \
  do {                                                                                          \
    _Pragma("unroll") for (int qt = 0; qt < 2; qt++) {                                          \
      _Pragma("unroll") for (int nt = 0; nt < 4; nt++) {                                        \
        const float e0 = __builtin_amdgcn_exp2f(scur[qt][nt][0]);                               \
        const float e1 = __builtin_amdgcn_exp2f(scur[qt][nt][1]);                               \
        const float e2 = __builtin_amdgcn_exp2f(scur[qt][nt][2]);                               \
        const float e3 = __builtin_amdgcn_exp2f(scur[qt][nt][3]);                               \
        bf16x2 p01, p23;                                                                        \
        p01[0] = (bf16)e0; p01[1] = (bf16)e1;                                                   \
        p23[0] = (bf16)e2; p23[1] = (bf16)e3;                                                   \
        pk[qt][nt][0] = __builtin_bit_cast(int, p01);                                           \
        pk[qt][nt][1] = __builtin_bit_cast(int, p23);                                           \
      }                                                                                         \
    }                                                                                           \
  } while (0)

#define PV(bu)                                                                                      \
  do {                                                                                              \
    const bf16* vs_ = Vs[bu];                                                                       \
    bf16x8 bV[4][2];                                                                                \
    _Pragma("unroll") for (int nd = 0; nd < 4; nd++) {                                              \
      bV[nd][0] = *reinterpret_cast<const bf16x8*>(vs_ + (nd * 16 + col) * 64 + (qd ^ c7) * 8);     \
      bV[nd][1] = *reinterpret_cast<const bf16x8*>(vs_ + (nd * 16 + col) * 64 + ((4 + qd) ^ c7) * 8); \
    }                                                                                               \
    _Pragma("unroll") for (int qt = 0; qt < 2; qt++) {                                              \
      _Pragma("unroll") for (int s = 0; s < 2; s++) {                                               \
        intx4 w;                                                                                    \
        w[0] = pk[qt][2 * s][0]; w[1] = pk[qt][2 * s][1];                                           \
        w[2] = pk[qt][2 * s + 1][0]; w[3] = pk[qt][2 * s + 1][1];                                   \
        const bf16x8 aP = __builtin_bit_cast(bf16x8, w);                                            \
        _Pragma("unroll") for (int nd = 0; nd < 4; nd++)                                            \
          oacc[qt][nd] = MFMA16(aP, bV[nd][s], oacc[qt][nd]);                                       \
        lacc[qt] = MFMA16(aP, bOnes, lacc[qt]);  /* row-sum of exp on matrix pipe */                \
      }                                                                                             \
    }                                                                                               \
  } while (0)

#define ITER5(cur, prv, stg, ti)                                       \
  do {                                                                 \
    asm volatile("s_waitcnt vmcnt(8)" ::: "memory");                   \
    __builtin_amdgcn_s_barrier();                                      \
    STAGE(stg, ((ti) + 3 <= 31) ? ((ti) + 3) : 31);                    \
    EXPPACK();                                                         \
    __builtin_amdgcn_s_setprio(1);                                     \
    QK(cur);                                                           \
    PV(prv);                                                           \
    __builtin_amdgcn_s_setprio(0);                                     \
  } while (0)

  STAGE(0, 0);
  STAGE(1, 1);
  STAGE(2, 2);
  STAGE(3, 3);
  asm volatile("s_waitcnt vmcnt(12)" ::: "memory");
  __builtin_amdgcn_s_barrier();
  QK(0);
  // tiles 1..30: 6 unrolled ring-5 groups
  for (int j = 1; j < 30; j += 5) {
    ITER5(1, 0, 4, j);
    ITER5(2, 1, 0, j + 1);
    ITER5(3, 2, 1, j + 2);
    ITER5(4, 3, 2, j + 3);
    ITER5(0, 4, 3, j + 4);
  }
  ITER5(1, 0, 4, 31);  // tile 31 (buf 1), PV(30) (buf 0)
  EXPPACK();
  __builtin_amdgcn_s_setprio(1);
  PV(1);  // tile 31 lives in buffer 31%5 == 1
  __builtin_amdgcn_s_setprio(0);

  // lane (qd,col) holds full exp-sums for its own rows qd*4+r in lacc[qt][r]
  const int bb = bh >> 4, h = bh & 15;
#pragma unroll
  for (int qt = 0; qt < 2; qt++) {
#pragma unroll
    for (int r = 0; r < 4; r++) {
      const float linv = 1.f / lacc[qt][r];
      const size_t m = (size_t)bb * 2048 + qr + qt * 16 + qd * 4 + r;
#pragma unroll
      for (int nd = 0; nd < 4; nd++)
        OB[m * 1024 + h * 64 + nd * 16 + col] = (bf16)(oacc[qt][nd][r] * linv);
    }
  }
#undef STAGE
#undef QK
#undef EXPPACK
#undef PV
#undef ITER5
}

// ---------------- LayerNorm ----------------
__global__ __launch_bounds__(256) void k_ln(const float* __restrict__ Yin, const float* __restrict__ gamma,
                                            const float* __restrict__ beta, float* __restrict__ out) {
  __shared__ float red[8];
  const int row = blockIdx.x, t = threadIdx.x;
  const float4 v = *reinterpret_cast<const float4*>(Yin + (size_t)row * 1024 + t * 4);
  float s = v.x + v.y + v.z + v.w;
  float ss = v.x * v.x + v.y * v.y + v.z * v.z + v.w * v.w;
#pragma unroll
  for (int d = 1; d < 64; d <<= 1) {
    s += __shfl_xor(s, d);
    ss += __shfl_xor(ss, d);
  }
  if ((t & 63) == 0) {
    red[t >> 6] = s;
    red[4 + (t >> 6)] = ss;
  }
  __syncthreads();
  s = red[0] + red[1] + red[2] + red[3];
  ss = red[4] + red[5] + red[6] + red[7];
  const float mu = s * (1.f / 1024.f);
  const float var = ss * (1.f / 1024.f) - mu * mu;
  const float rs = rsqrtf(var + 1e-6f);
  const float4 g = *reinterpret_cast<const float4*>(gamma + t * 4);
  const float4 bt = *reinterpret_cast<const float4*>(beta + t * 4);
  float4 o;
  o.x = (v.x - mu) * rs * g.x + bt.x;
  o.y = (v.y - mu) * rs * g.y + bt.y;
  o.z = (v.z - mu) * rs * g.z + bt.z;
  o.w = (v.w - mu) * rs * g.w + bt.w;
  *reinterpret_cast<float4*>(out + (size_t)row * 1024 + t * 4) = o;
}

extern "C" void kernel_launch(void* const* d_in, const int* in_sizes, int n_in,
                              void* d_out, int out_size, void* d_ws, size_t ws_size,
                              hipStream_t stream) {
  (void)in_sizes; (void)n_in; (void)out_size; (void)ws_size;
  const float* x = (const float*)d_in[0];
  const float* Wq = (const float*)d_in[1];
  const float* Wk = (const float*)d_in[2];
  const float* Wv = (const float*)d_in[3];
  const float* Wo = (const float*)d_in[4];
  const float* gamma = (const float*)d_in[5];
  const float* beta = (const float*)d_in[6];

  char* ws = (char*)d_ws;
  const size_t MB = 1ull << 20;
  bf16* XB = (bf16*)(ws);            // 0-8MB (dead after k_gemm<0>)
  bf16* OB = (bf16*)(ws);            // 0-8MB
  bf16* WT = (bf16*)(ws + 8 * MB);   // 8-16MB
  bf16* QB = (bf16*)(ws + 16 * MB);  // 16-24MB
  bf16* KB = (bf16*)(ws + 24 * MB);  // 24-32MB
  bf16* VTB = (bf16*)(ws + 32 * MB); // 32-40MB
  float* Y = (float*)(ws + 16 * MB); // reuses QB/KB region after attn consumed them

  k_prep<<<dim3(32, 32, 8), dim3(32, 8), 0, stream>>>(x, Wq, Wk, Wv, Wo, XB, WT);
  k_gemm<0><<<dim3(32, 24), 256, 0, stream>>>(XB, WT, nullptr, nullptr, QB, KB, VTB);
  k_attn<<<512, 256, 0, stream>>>(QB, KB, VTB, OB);
  k_gemm_op<<<dim3(64, 8), 256, 0, stream>>>(OB, WT + (size_t)3072 * 1024, x, Y);
  k_ln<<<4096, 256, 0, stream>>>(Y, gamma, beta, (float*)d_out);
}